// Round 7
// baseline (539.197 us; speedup 1.0000x reference)
//
#include <hip/hip_runtime.h>
#include <hip/hip_bf16.h>

// RelativeAttention: out = ((softmax(((QK^T)*s + Q.rel)*s with mask) V) Wo + bo
// B=4 S=1024 D=1024 H=16 dk=64.  All matmuls in bf16 MFMA (16x16x32), f32 accum.

typedef unsigned short u16;
typedef unsigned int u32;
typedef unsigned long long u64;
typedef __attribute__((ext_vector_type(8))) short bf16x8;
typedef __attribute__((ext_vector_type(4))) float f32x4;

#define SB 1024
#define DM 1024
#define NHD 16
#define DKH 64
#define NBATCH 4

// issue-order pin WITHOUT memory clobber (memory-clobber asm makes the waitcnt
// pass drain vmcnt conservatively -> kills prefetch; sched_barrier does not)
#define PIN() __builtin_amdgcn_sched_barrier(0)

__device__ __forceinline__ u16 f2bf(float x) {
  union { __hip_bfloat16 b; u16 u; } c;
  c.b = __float2bfloat16(x);
  return c.u;
}

__device__ __forceinline__ f32x4 mfma16(bf16x8 a, bf16x8 b, f32x4 c) {
  return __builtin_amdgcn_mfma_f32_16x16x32_bf16(a, b, c, 0, 0, 0);
}

__device__ __forceinline__ bf16x8 cvt8r(float4 v0, float4 v1) {
  bf16x8 r;
  r[0] = (short)f2bf(v0.x); r[1] = (short)f2bf(v0.y);
  r[2] = (short)f2bf(v0.z); r[3] = (short)f2bf(v0.w);
  r[4] = (short)f2bf(v1.x); r[5] = (short)f2bf(v1.y);
  r[6] = (short)f2bf(v1.z); r[7] = (short)f2bf(v1.w);
  return r;
}

// ---------------- f32 -> bf16 for the 3 input activations ----------------
__global__ void ra_convert_in(const float* __restrict__ q, const float* __restrict__ k,
                              const float* __restrict__ v,
                              u16* __restrict__ Xq, u16* __restrict__ Xk, u16* __restrict__ Xv)
{
  const int z = blockIdx.y;
  const float* src = (z == 0) ? q : (z == 1) ? k : v;
  u16* dst = (z == 0) ? Xq : (z == 1) ? Xk : Xv;
  const int n4 = NBATCH * SB * DM / 4;
  int idx = blockIdx.x * blockDim.x + threadIdx.x;
  int stride = gridDim.x * blockDim.x;
  for (int i = idx; i < n4; i += stride) {
    float4 v4 = *((const float4*)src + i);
    uint2 o;
    o.x = (u32)f2bf(v4.x) | ((u32)f2bf(v4.y) << 16);
    o.y = (u32)f2bf(v4.z) | ((u32)f2bf(v4.w) << 16);
    *((uint2*)dst + i) = o;
  }
}

// ---------------- W (f32 [k][n]) -> W^T (bf16 [n][k]) ----------------
__global__ void ra_transpose_w(const float* __restrict__ Wq, const float* __restrict__ Wk,
                               const float* __restrict__ Wv, const float* __restrict__ Wo,
                               u16* __restrict__ WqT, u16* __restrict__ WkT,
                               u16* __restrict__ WvT, u16* __restrict__ WoT)
{
  const int z = blockIdx.z;
  const float* W = (z == 0) ? Wq : (z == 1) ? Wk : (z == 2) ? Wv : Wo;
  u16* WT = (z == 0) ? WqT : (z == 1) ? WkT : (z == 2) ? WvT : WoT;
  __shared__ float tile[32][33];
  const int x0 = blockIdx.x * 32, y0 = blockIdx.y * 32;
  const int tx = threadIdx.x, ty = threadIdx.y;
#pragma unroll
  for (int yy = 0; yy < 4; ++yy) {
    int r = ty + yy * 8;
    tile[r][tx] = W[(size_t)(y0 + r) * DM + x0 + tx];
  }
  __syncthreads();
#pragma unroll
  for (int yy = 0; yy < 4; ++yy) {
    int r = ty + yy * 8;
    WT[(size_t)(x0 + r) * DM + y0 + tx] = f2bf(tile[tx][r]);
  }
}

// ---------------- shared 128x128x1024 bf16 GEMM core ----------------
__device__ __forceinline__ void gemm_core_128(const u16* __restrict__ A, const u16* __restrict__ Bt,
                                              int bm0, int bn0, u16* sh, f32x4 (&acc)[4][4])
{
  u16* As = sh;             // [128][72]
  u16* Bs = sh + 128 * 72;  // [128][72]
  const int tid = threadIdx.x;
  const int lane = tid & 63, wid = tid >> 6;
  const int l15 = lane & 15, l4 = lane >> 4;
  const int wr = (wid >> 1) * 64, wc = (wid & 1) * 64;
  for (int k0 = 0; k0 < DM; k0 += 64) {
#pragma unroll
    for (int it = 0; it < 4; ++it) {
      int c = tid + it * 256;
      int rw = c >> 3, kc = c & 7;
      *(uint4*)(As + rw * 72 + kc * 8) = *(const uint4*)(A + (size_t)(bm0 + rw) * DM + k0 + kc * 8);
      *(uint4*)(Bs + rw * 72 + kc * 8) = *(const uint4*)(Bt + (size_t)(bn0 + rw) * DM + k0 + kc * 8);
    }
    __syncthreads();
#pragma unroll
    for (int kf = 0; kf < 2; ++kf) {
      bf16x8 a[4], b[4];
#pragma unroll
      for (int mf = 0; mf < 4; ++mf)
        a[mf] = *(const bf16x8*)(As + (wr + mf * 16 + l15) * 72 + kf * 32 + l4 * 8);
#pragma unroll
      for (int nf = 0; nf < 4; ++nf)
        b[nf] = *(const bf16x8*)(Bs + (wc + nf * 16 + l15) * 72 + kf * 32 + l4 * 8);
#pragma unroll
      for (int mf = 0; mf < 4; ++mf)
#pragma unroll
        for (int nf = 0; nf < 4; ++nf)
          acc[mf][nf] = mfma16(a[mf], b[nf], acc[mf][nf]);
    }
    __syncthreads();
  }
}

// ---------------- projections: q/k -> [bh][s][dk], v -> [bh][dk][s] ----------------
__global__ __launch_bounds__(256, 2)
void ra_proj_gemm(const u16* __restrict__ Xq, const u16* __restrict__ Xk, const u16* __restrict__ Xv,
                  const u16* __restrict__ WqT, const u16* __restrict__ WkT, const u16* __restrict__ WvT,
                  const float* __restrict__ bq, const float* __restrict__ bk, const float* __restrict__ bv,
                  u16* __restrict__ q_ws, u16* __restrict__ k_ws, u16* __restrict__ vT_ws)
{
  __shared__ alignas(16) u16 sh[128 * 72 * 2];
  const int mode = blockIdx.z;
  const u16* A  = (mode == 0) ? Xq : (mode == 1) ? Xk : Xv;
  const u16* Bt = (mode == 0) ? WqT : (mode == 1) ? WkT : WvT;
  const float* bias = (mode == 0) ? bq : (mode == 1) ? bk : bv;
  const int bm0 = blockIdx.x * 128, bn0 = blockIdx.y * 128;
  f32x4 acc[4][4] = {};
  gemm_core_128(A, Bt, bm0, bn0, sh, acc);
  const int tid = threadIdx.x;
  const int lane = tid & 63, wid = tid >> 6;
  const int l15 = lane & 15, l4 = lane >> 4;
  const int wr = (wid >> 1) * 64, wc = (wid & 1) * 64;
  const int b_idx = bm0 >> 10;
  const int srow0 = bm0 & (SB - 1);
  if (mode < 2) {
    u16* outp = (mode == 0) ? q_ws : k_ws;
#pragma unroll
    for (int nf = 0; nf < 4; ++nf) {
      int nn = bn0 + wc + nf * 16 + l15;
      float bv_ = bias[nn];
      int h = nn >> 6, d = nn & 63;
#pragma unroll
      for (int mf = 0; mf < 4; ++mf)
#pragma unroll
        for (int r = 0; r < 4; ++r) {
          int m = wr + mf * 16 + l4 * 4 + r;
          outp[((size_t)(b_idx * NHD + h) * SB + srow0 + m) * DKH + d] = f2bf(acc[mf][nf][r] + bv_);
        }
    }
  } else {
    u16* ct = sh;  // [128][136]
#pragma unroll
    for (int nf = 0; nf < 4; ++nf) {
      int nl = wc + nf * 16 + l15;
      float bv_ = bias[bn0 + nl];
#pragma unroll
      for (int mf = 0; mf < 4; ++mf)
#pragma unroll
        for (int r = 0; r < 4; ++r) {
          int m = wr + mf * 16 + l4 * 4 + r;
          ct[nl * 136 + m] = f2bf(acc[mf][nf][r] + bv_);
        }
    }
    __syncthreads();
#pragma unroll
    for (int it = 0; it < 8; ++it) {
      int c = tid + it * 256;
      int n = c >> 4, mc2 = c & 15;
      uint4 v = *(const uint4*)(ct + n * 136 + mc2 * 8);
      int nn = bn0 + n;
      int h = nn >> 6, d = nn & 63;
      *(uint4*)(vT_ws + ((size_t)(b_idx * NHD + h) * DKH + d) * SB + srow0 + mc2 * 8) = v;
    }
  }
}

// ---------------- final projection: out = x @ Wo + bo (f32 out) ----------------
__global__ __launch_bounds__(256, 2)
void ra_out_gemm(const u16* __restrict__ X, const u16* __restrict__ WoT,
                 const float* __restrict__ bo, float* __restrict__ out)
{
  __shared__ alignas(16) u16 sh[128 * 72 * 2];
  const int bm0 = blockIdx.x * 128, bn0 = blockIdx.y * 128;
  f32x4 acc[4][4] = {};
  gemm_core_128(X, WoT, bm0, bn0, sh, acc);
  const int tid = threadIdx.x;
  const int lane = tid & 63, wid = tid >> 6;
  const int l15 = lane & 15, l4 = lane >> 4;
  const int wr = (wid >> 1) * 64, wc = (wid & 1) * 64;
#pragma unroll
  for (int nf = 0; nf < 4; ++nf) {
    int nn = bn0 + wc + nf * 16 + l15;
    float bv_ = bo[nn];
#pragma unroll
    for (int mf = 0; mf < 4; ++mf)
#pragma unroll
      for (int r = 0; r < 4; ++r) {
        int m = wr + mf * 16 + l4 * 4 + r;
        out[(size_t)(bm0 + m) * DM + nn] = acc[mf][nf][r] + bv_;
      }
  }
}

// ---------------- mask -> bitmask (1 bit per j) ----------------
__global__ __launch_bounds__(256)
void ra_mask_pack(const int* __restrict__ mask, u32* __restrict__ mb)
{
  const size_t t = (size_t)blockIdx.x * 256 + threadIdx.x;  // 4M threads
  const int lane = threadIdx.x & 63;
  u64 b = __ballot(mask[t] != 0);
  if (lane == 0) *(u64*)(mb + (t >> 6) * 2) = b;
}

// ---------------- fused attention v7 ----------------
// v6 decomposition (16 waves: wave w owns head bh=w for s1/PV, i-plane i0+w for s2;
// s2 exchanged via small dbuf fp16 LDS tile), but with:
//  * raw s_barrier + lgkmcnt(0)-only wait  -> global loads SURVIVE the barrier
//    (one barrier per j-16 tile; dbuf puts writes 2 barriers from their readers)
//  * sched_barrier(0)-only pins (no memory clobber -> no forced vmcnt drains)
//  * 2-deep rel/K prefetch with named A/B register sets; 1-deep V; mask 1 word/2 tiles
//  * defer-max online softmax (THR=8): common path has no rescale, no max-shfls
__global__ __launch_bounds__(1024, 1)
void ra_attn(const u16* __restrict__ q_ws, const u16* __restrict__ k_ws,
             const u16* __restrict__ vT_ws, const u32* __restrict__ mb,
             const float* __restrict__ rel, u16* __restrict__ x_ws)
{
  // s2t[buf][i][bh][j]: fp16, bh-stride 18, i-stride 292 (bank-spread; proven in v6)
  __shared__ _Float16 s2t[2][16 * 292 + 8];

  const int tid = threadIdx.x, wid = tid >> 6, lane = tid & 63;
  const int l15 = lane & 15, l4 = lane >> 4;
  const int g = blockIdx.y, i0 = blockIdx.x * 16;
  const int bh_g = g * NHD + wid;                  // this wave's head
  const float scl1 = 0.125f, scl2 = 0.015625f;     // 1/sqrt(dk), 1/dk

  // ---- persistent q fragments ----
  bf16x8 q1[2], q2[2];
#pragma unroll
  for (int kf = 0; kf < 2; ++kf) {
    q1[kf] = *(const bf16x8*)(q_ws + ((size_t)bh_g * SB + i0 + l15) * DKH + kf * 32 + l4 * 8);
    q2[kf] = *(const bf16x8*)(q_ws + ((size_t)(g * NHD + l15) * SB + i0 + wid) * DKH + kf * 32 + l4 * 8);
  }

  const u16* kbase = k_ws + (size_t)bh_g * SB * DKH;
  const u16* vbase = vT_ws + (size_t)bh_g * DKH * SB;
  const float* rbase = rel + (size_t)(i0 + wid) * SB * DKH;
  const u32* mbase = mb + ((size_t)g * SB + i0 + l15) * 32;

  // ---- prefetch register sets ----
  bf16x8 kaA[2], kaB[2];     // K[j=l15][d], tiles 2t / 2t+1
  float4 rrA[4], rrB[4];     // rel[i0+wid][jb+l15][d] f32
  uint2  vb2[4];             // V (1-deep): vT[d=df*16+l15][jb + l4*4 ..]
  u32    mw;                 // mask word (2 tiles)

  // prologue: tiles 0 (A) and 1 (B)
#pragma unroll
  for (int kf = 0; kf < 2; ++kf) {
    kaA[kf] = *(const bf16x8*)(kbase + (size_t)l15 * DKH + kf * 32 + l4 * 8);
    kaB[kf] = *(const bf16x8*)(kbase + (size_t)(16 + l15) * DKH + kf * 32 + l4 * 8);
  }
  {
    const float* rp = rbase + (size_t)l15 * DKH + l4 * 8;
    rrA[0] = *(const float4*)rp;        rrA[1] = *(const float4*)(rp + 4);
    rrA[2] = *(const float4*)(rp + 32); rrA[3] = *(const float4*)(rp + 36);
    const float* rp2 = rbase + (size_t)(16 + l15) * DKH + l4 * 8;
    rrB[0] = *(const float4*)rp2;        rrB[1] = *(const float4*)(rp2 + 4);
    rrB[2] = *(const float4*)(rp2 + 32); rrB[3] = *(const float4*)(rp2 + 36);
  }
#pragma unroll
  for (int df = 0; df < 4; ++df)
    vb2[df] = *(const uint2*)(vbase + (size_t)(df * 16 + l15) * SB + l4 * 4);
  mw = mbase[0];
  PIN();

  f32x4 acc_o[4] = {};
  float m_run = -1e30f, l_run = 0.f;

  // per-tile body: RR/KA = register set, BUF = s2t buffer, MSHIFT = mask bit base,
  // TPK = tile index to prefetch rel/K into this set, TPV = tile index to prefetch V
#define TILE_BODY(RR, KA, BUF, MSHIFT, TPK, TPV)                                      \
  {                                                                                   \
    /* s2 = mfma(rel_j, q2): lane l15 = bh, regs = j; -> fp16 LDS */                  \
    bf16x8 rb0 = cvt8r(RR[0], RR[1]);                                                 \
    bf16x8 rb1 = cvt8r(RR[2], RR[3]);                                                 \
    f32x4 t2 = {};                                                                    \
    t2 = mfma16(rb0, q2[0], t2);                                                      \
    t2 = mfma16(rb1, q2[1], t2);                                                      \
    union { _Float16 h[4]; uint2 u; } w2;                                             \
    _Pragma("unroll") for (int r = 0; r < 4; ++r) w2.h[r] = (_Float16)(t2[r] * scl1); \
    *(uint2*)&s2t[BUF][wid * 292 + l15 * 18 + l4 * 4] = w2.u;                         \
    /* reissue rel -> this set (2 tiles ahead) */                                     \
    {                                                                                 \
      const float* rp = rbase + (size_t)((TPK) * 16 + l15) * DKH + l4 * 8;            \
      RR[0] = *(const float4*)rp;        RR[1] = *(const float4*)(rp + 4);            \
      RR[2] = *(const float4*)(rp + 32); RR[3] = *(const float4*)(rp + 36);           \
    }                                                                                 \
    PIN();                                                                            \
    /* s1 = mfma(K_j, q1): lane l15 = i, regs = j */                                  \
    f32x4 sc1 = {};                                                                   \
    sc1 = mfma16(KA[0], q1[0], sc1);                                                  \
    sc1 = mfma16(KA[1], q1[1], sc1);                                                  \
    /* reissue K -> this set */                                                       \
    KA[0] = *(const bf16x8*)(kbase + (size_t)((TPK) * 16 + l15) * DKH + l4 * 8);      \
    KA[1] = *(const bf16x8*)(kbase + (size_t)((TPK) * 16 + l15) * DKH + 32 + l4 * 8); \
    PIN();                                                                            \
    /* raw barrier: drain ONLY LDS (my s2 write); vmem prefetch stays in flight */    \
    asm volatile("s_waitcnt lgkmcnt(0)");                                             \
    __builtin_amdgcn_sched_barrier(0);                                                \
    __builtin_amdgcn_s_barrier();                                                     \
    __builtin_amdgcn_sched_barrier(0);                                                \
    {                                                                                 \
      uint2 s2u = *(const uint2*)&s2t[BUF][l15 * 292 + wid * 18 + l4 * 4];            \
      union { uint2 u; _Float16 h[4]; } s2c; s2c.u = s2u;                             \
      float sv0 = sc1[0] * scl2 + (float)s2c.h[0];                                    \
      float sv1 = sc1[1] * scl2 + (float)s2c.h[1];                                    \
      float sv2 = sc1[2] * scl2 + (float)s2c.h[2];                                    \
      float sv3 = sc1[3] * scl2 + (float)s2c.h[3];                                    \
      const u32 mbits = mw >> (MSHIFT);                                               \
      sv0 = (mbits & 1u) ? sv0 : -1e9f;                                               \
      sv1 = (mbits & 2u) ? sv1 : -1e9f;                                               \
      sv2 = (mbits & 4u) ? sv2 : -1e9f;                                               \
      sv3 = (mbits & 8u) ? sv3 : -1e9f;                                               \
      float tmax = fmaxf(fmaxf(sv0, sv1), fmaxf(sv2, sv3));                           \
      if (!__all(tmax <= m_run + 8.0f)) {   /* rare rescale path */                   \
        float rmax = fmaxf(tmax, __shfl_xor(tmax, 16));                               \
        rmax = fmaxf(rmax, __shfl_xor(rmax, 32));                                     \
        float m_new = fmaxf(m_run, rmax);                                             \
        float fsc = __expf(m_run - m_new);                                            \
        l_run *= fsc; m_run = m_new;                                                  \
        _Pragma("unroll") for (int df = 0; df < 4; ++df) {                            \
          acc_o[df][0] *= fsc; acc_o[df][1] *= fsc;                                   \
          acc_o[df][2] *= fsc; acc_o[df][3] *= fsc;                                   \
        }                                                                             \
      }                                                                               \
      float p0 = __expf(sv0 - m_run), p1 = __expf(sv1 - m_run);                       \
      float p2 = __expf(sv2 - m_run), p3 = __expf(sv3 - m_run);                       \
      float psum = (p0 + p1) + (p2 + p3);                                             \
      psum += __shfl_xor(psum, 16);                                                   \
      psum += __shfl_xor(psum, 32);                                                   \
      l_run += psum;                                                                  \
      union { bf16x8 v; u32 w[4]; } pk;                                               \
      pk.w[0] = (u32)f2bf(p0) | ((u32)f2bf(p1) << 16);                                \
      pk.w[1] = (u32)f2bf(p2) | ((u32)f2bf(p3) << 16);                                \
      pk.w[2] = 0; pk.w[3] = 0;                                                       \
      /* PV (swapped): O^T[d][i] += mfma(A=V[d][j], B=P[i][j]); lane l15 = i */       \
      _Pragma("unroll") for (int df = 0; df < 4; ++df) {                              \
        union { bf16x8 v; uint2 q[2]; } vv;                                           \
        vv.q[0] = vb2[df];                                                            \
        vv.q[1] = make_uint2(0, 0);                                                   \
        acc_o[df] = mfma16(vv.v, pk.v, acc_o[df]);                                    \
      }                                                                               \
    }                                                                                 \
    /* reissue V (1 tile ahead) */                                                    \
    _Pragma("unroll") for (int df = 0; df < 4; ++df)                                  \
      vb2[df] = *(const uint2*)(vbase + (size_t)(df * 16 + l15) * SB + (TPV) * 16 + l4 * 4); \
    PIN();                                                                            \
  }

  for (int t = 0; t < 32; ++t) {
    const int tpA = (2 * t + 2 < 64) ? 2 * t + 2 : 63;
    const int tpB = (2 * t + 3 < 64) ? 2 * t + 3 : 63;
    const int tvB = (2 * t + 2 < 64) ? 2 * t + 2 : 63;
    TILE_BODY(rrA, kaA, 0, (l4 * 4), tpA, (2 * t + 1));
    const u32 mwN = mbase[(t + 1 < 32) ? (t + 1) : 31];
    TILE_BODY(rrB, kaB, 1, (16 + l4 * 4), tpB, tvB);
    mw = mwN;
  }
#undef TILE_BODY

  // ---- epilogue: per-lane normalize (row i = l15), write x bf16 8B/lane ----
  const float inv = 1.f / l_run;
#pragma unroll
  for (int df = 0; df < 4; ++df) {
    union { u16 h[4]; uint2 u; } o;
#pragma unroll
    for (int r = 0; r < 4; ++r) o.h[r] = f2bf(acc_o[df][r] * inv);
    *(uint2*)(x_ws + ((size_t)g * SB + i0 + l15) * DM + wid * DKH + df * 16 + l4 * 4) = o.u;
  }
}

// ---------------- launch ----------------
extern "C" void kernel_launch(void* const* d_in, const int* in_sizes, int n_in,
                              void* d_out, int out_size, void* d_ws, size_t ws_size,
                              hipStream_t stream) {
  const float* query = (const float*)d_in[0];
  const float* key_  = (const float*)d_in[1];
  const float* value = (const float*)d_in[2];
  const int*   mask  = (const int*)d_in[3];
  const float* rel   = (const float*)d_in[4];
  const float* Wq = (const float*)d_in[5];
  const float* Wk = (const float*)d_in[6];
  const float* Wv = (const float*)d_in[7];
  const float* Wo = (const float*)d_in[8];
  const float* bq = (const float*)d_in[9];
  const float* bk = (const float*)d_in[10];
  const float* bv = (const float*)d_in[11];
  const float* bo = (const float*)d_in[12];
  float* out = (float*)d_out;
  char* ws = (char*)d_ws;

  u16* Xq   = (u16*)(ws + (0ull));
  u16* Xk   = (u16*)(ws + (8ull << 20));
  u16* Xv   = (u16*)(ws + (16ull << 20));
  u16* WqT  = (u16*)(ws + (24ull << 20));
  u16* WkT  = (u16*)(ws + (26ull << 20));
  u16* WvT  = (u16*)(ws + (28ull << 20));
  u16* WoT  = (u16*)(ws + (30ull << 20));
  u16* q_ws = (u16*)(ws + (32ull << 20));
  u16* k_ws = (u16*)(ws + (40ull << 20));
  u16* vT_ws= (u16*)(ws + (48ull << 20));
  u16* x_ws = (u16*)(ws + (56ull << 20));
  u32* mb   = (u32*)(ws + (16ull << 20));   // overlays Xv (dead after proj)

  ra_convert_in<<<dim3(1024, 3), 256, 0, stream>>>(query, key_, value, Xq, Xk, Xv);
  ra_transpose_w<<<dim3(32, 32, 4), dim3(32, 8), 0, stream>>>(Wq, Wk, Wv, Wo, WqT, WkT, WvT, WoT);
  ra_proj_gemm<<<dim3(32, 8, 3), 256, 0, stream>>>(Xq, Xk, Xv, WqT, WkT, WvT, bq, bk, bv,
                                                   q_ws, k_ws, vT_ws);
  ra_mask_pack<<<16384, 256, 0, stream>>>(mask, mb);
  ra_attn<<<dim3(64, 4), 1024, 0, stream>>>(q_ws, k_ws, vT_ws, mb, rel, x_ws);
  ra_out_gemm<<<dim3(32, 8), 256, 0, stream>>>(x_ws, WoT, bo, out);
}